// Round 5
// baseline (303.565 us; speedup 1.0000x reference)
//
#include <hip/hip_runtime.h>

#define N_NODES 2048
#define N_EDGES 16384
#define TT 12
#define BT 96          // B*T
#define CC 64
#define OUT_DIM 64
#define EPSV 1e-7f
#define NTILE (32 * BT)   // 3072 transpose blocks

typedef _Float16 half4v __attribute__((ext_vector_type(4)));

// ---------------- dispatch 1: zero deg ----------------
__global__ __launch_bounds__(256) void k_zero(int* __restrict__ deg) {
    deg[blockIdx.x * 256 + threadIdx.x] = 0;
}

// ---- dispatch 2: transpose [B,C,T,N]->h16[bt][n][c]  +  deg count  +  ef->fp16 ----
__global__ __launch_bounds__(256) void k_trans(const float* __restrict__ nf, _Float16* __restrict__ h,
                                               const int* __restrict__ dst, int* __restrict__ deg,
                                               const float* __restrict__ ef, _Float16* __restrict__ ef16) {
    int raw = blockIdx.x;
    int tid = threadIdx.x;
    if (raw >= NTILE) {
        int aux = raw - NTILE;
        if (aux < 64) {                      // degree count (16384 edges)
            int e = aux * 256 + tid;
            atomicAdd(&deg[dst[e]], 1);
        } else {                             // ef fp32 -> fp16 (1M elements)
            int a = (aux - 64) * 256 + tid;  // 0..65535
            const float4* s4 = (const float4*)ef;
            half4v* d4 = (half4v*)ef16;
#pragma unroll
            for (int p = 0; p < 4; ++p) {
                float4 v = s4[a + p * 65536];
                half4v o;
                o.x = (_Float16)v.x; o.y = (_Float16)v.y; o.z = (_Float16)v.z; o.w = (_Float16)v.w;
                d4[a + p * 65536] = o;
            }
        }
        return;
    }
    __shared__ float lds[64][65];
    int logical = (raw & 7) * 384 + (raw >> 3);   // XCD-contiguous bt ranges
    int bt = logical >> 5;
    int nt = logical & 31;
    int b = bt / TT, t = bt - b * TT;
    int n4 = (tid & 15) << 2;
    int cr = tid >> 4;
    const float* base = nf + ((size_t)(b * CC) * TT + t) * N_NODES + nt * 64;
#pragma unroll
    for (int p = 0; p < 4; ++p) {
        int c = cr + p * 16;
        float4 v = *(const float4*)(base + (size_t)c * TT * N_NODES + n4);
        lds[c][n4 + 0] = v.x; lds[c][n4 + 1] = v.y; lds[c][n4 + 2] = v.z; lds[c][n4 + 3] = v.w;
    }
    __syncthreads();
    int c4 = (tid & 15) << 2;
    int nr = tid >> 4;
    _Float16* hb = h + ((size_t)bt * N_NODES + nt * 64) * CC;
#pragma unroll
    for (int p = 0; p < 4; ++p) {
        int n = nr + p * 16;
        half4v o;
        o.x = (_Float16)lds[c4 + 0][n]; o.y = (_Float16)lds[c4 + 1][n];
        o.z = (_Float16)lds[c4 + 2][n]; o.w = (_Float16)lds[c4 + 3][n];
        *(half4v*)(hb + (size_t)n * CC + c4) = o;
    }
}

// ---------------- dispatch 3: scan deg -> offs, cur ----------------
__global__ __launch_bounds__(1024) void k_scan(const int* __restrict__ deg, int* __restrict__ offs,
                                               int* __restrict__ cur) {
    __shared__ int sc[1024];
    int t = threadIdx.x;
    int d0 = deg[2 * t], d1 = deg[2 * t + 1];
    int p = d0 + d1;
    sc[t] = p;
    __syncthreads();
    for (int off = 1; off < 1024; off <<= 1) {
        int v = (t >= off) ? sc[t - off] : 0;
        __syncthreads();
        sc[t] += v;
        __syncthreads();
    }
    int excl = sc[t] - p;
    offs[2 * t] = excl;         cur[2 * t] = excl;
    offs[2 * t + 1] = excl + d0; cur[2 * t + 1] = excl + d0;
    if (t == 1023) offs[N_NODES] = sc[t];
}

// ---------------- dispatch 4: CSR fill ----------------
__global__ __launch_bounds__(256) void k_fill(const int* __restrict__ dst, const int* __restrict__ src,
                                              int* cur, int2* __restrict__ csr) {
    int e = blockIdx.x * 256 + threadIdx.x;
    int d = dst[e];
    int pos = atomicAdd(&cur[d], 1);
    csr[pos] = make_int2(e, src[e]);
}

// ---------------- dispatch 5: fused aggregate + matmul + transposed store ----------------
__global__ __launch_bounds__(256, 8) void k_agg(const _Float16* __restrict__ h,
                                                const int* __restrict__ offs,
                                                const int2* __restrict__ csr,
                                                const _Float16* __restrict__ ef16,
                                                const float* __restrict__ W,
                                                const float* __restrict__ bias,
                                                float* __restrict__ out) {
    __shared__ float fs[64 * 64];     // XOR-swizzled tile of (h + agg)

    int tid = threadIdx.x;
    int raw = blockIdx.x;
    int logical = (raw & 7) * 384 + (raw >> 3);   // same XCD mapping as transpose
    int bt = logical >> 5;
    int nt = logical & 31;
    int b = bt / TT, t = bt - b * TT;
    int wave = tid >> 6, lane = tid & 63;
    int wbase = __builtin_amdgcn_readfirstlane(wave * 16);
    int ntb = __builtin_amdgcn_readfirstlane(nt * 64);

    const _Float16* hl = h + (size_t)bt * (N_NODES * CC) + lane;
    const _Float16* efl = ef16 + lane;

    for (int g = 0; g < 2; ++g) {
        int nb = ntb + wbase + g * 8;
        int kk[8], ke[8], pe[8], ps[8];
        float den[8], ws[8], hn[8];
#pragma unroll
        for (int j = 0; j < 8; ++j) {
            kk[j] = __builtin_amdgcn_readfirstlane(offs[nb + j]);
            ke[j] = __builtin_amdgcn_readfirstlane(offs[nb + j + 1]);
            den[j] = 0.f; ws[j] = 0.f;
            hn[j] = (float)hl[(size_t)(nb + j) * CC];
            pe[j] = 0; ps[j] = 0;
            if (kk[j] < ke[j]) {                 // prefetch first pair (scalar)
                int2 pr = csr[kk[j]];
                pe[j] = __builtin_amdgcn_readfirstlane(pr.x);
                ps[j] = __builtin_amdgcn_readfirstlane(pr.y);
            }
        }
        while (kk[0] < ke[0] || kk[1] < ke[1] || kk[2] < ke[2] || kk[3] < ke[3] ||
               kk[4] < ke[4] || kk[5] < ke[5] || kk[6] < ke[6] || kk[7] < ke[7]) {
            float hs[8], ev[8];
            bool on[8];
#pragma unroll
            for (int j = 0; j < 8; ++j) {        // up to 16 independent gathers in flight
                on[j] = kk[j] < ke[j];
                if (on[j]) {
                    hs[j] = (float)hl[(size_t)ps[j] * CC];
                    ev[j] = (float)efl[(size_t)pe[j] * CC];
                    kk[j]++;
                }
            }
#pragma unroll
            for (int j = 0; j < 8; ++j) {        // prefetch next pairs (overlaps gathers)
                if (kk[j] < ke[j]) {
                    int2 pr = csr[kk[j]];
                    pe[j] = __builtin_amdgcn_readfirstlane(pr.x);
                    ps[j] = __builtin_amdgcn_readfirstlane(pr.y);
                }
            }
#pragma unroll
            for (int j = 0; j < 8; ++j) {
                if (on[j]) {
                    float msg = fmaxf(hs[j] + ev[j], 0.f) + EPSV;
                    float pw = __expf(msg);      // max cancels in softmax; msg <= ~6
                    den[j] += pw;
                    ws[j] = fmaf(pw, msg, ws[j]);
                }
            }
        }
#pragma unroll
        for (int j = 0; j < 8; ++j) {
            int nl = wbase + g * 8 + j;
            float agg = den[j] > 0.f ? ws[j] / den[j] : 0.f;
            fs[nl * 64 + (lane ^ (nl & 31))] = hn[j] + agg;
        }
    }
    __syncthreads();

    float acc[16];
#pragma unroll
    for (int j = 0; j < 16; ++j) acc[j] = bias[wbase + j];          // s_load
    for (int c = 0; c < 64; ++c) {
        float v = fs[lane * 64 + (c ^ (lane & 31))];                // conflict-free
#pragma unroll
        for (int j = 0; j < 16; ++j)
            acc[j] = fmaf(v, W[c * 64 + wbase + j], acc[j]);        // uniform -> s_load
    }
    size_t obase = ((size_t)(b * OUT_DIM + wbase) * TT + t) * N_NODES + ntb + lane;
#pragma unroll
    for (int j = 0; j < 16; ++j)
        out[obase + (size_t)j * (TT * N_NODES)] = acc[j];
}

extern "C" void kernel_launch(void* const* d_in, const int* in_sizes, int n_in,
                              void* d_out, int out_size, void* d_ws, size_t ws_size,
                              hipStream_t stream) {
    const float* nf  = (const float*)d_in[0];   // [B,C,T,N]
    const float* ef  = (const float*)d_in[1];   // [E,1,1,C]
    const int*   src = (const int*)d_in[2];
    const int*   dst = (const int*)d_in[3];
    const float* W   = (const float*)d_in[4];   // [C,OUT]
    const float* bia = (const float*)d_in[5];   // [OUT]
    float* out = (float*)d_out;

    _Float16* h    = (_Float16*)d_ws;                        // BT*N*C halves = 24 MiB
    _Float16* ef16 = h + (size_t)BT * N_NODES * CC;          // E*C halves = 2 MiB
    int2* csr      = (int2*)(ef16 + (size_t)N_EDGES * CC);   // 8B-aligned
    int* deg       = (int*)(csr + N_EDGES);
    int* offs      = deg + N_NODES;                          // N+1
    int* cur       = offs + (N_NODES + 1);

    k_zero<<<N_NODES / 256, 256, 0, stream>>>(deg);
    k_trans<<<NTILE + 64 + 256, 256, 0, stream>>>(nf, h, dst, deg, ef, ef16);
    k_scan<<<1, 1024, 0, stream>>>(deg, offs, cur);
    k_fill<<<N_EDGES / 256, 256, 0, stream>>>(dst, src, cur, csr);
    k_agg<<<NTILE, 256, 0, stream>>>(h, offs, csr, ef16, W, bia, out);
}

// Round 6
// 261.550 us; speedup vs baseline: 1.1606x; 1.1606x over previous
//
#include <hip/hip_runtime.h>

#define N_NODES 2048
#define N_EDGES 16384
#define TT 12
#define BT 96          // B*T
#define CC 64
#define OUT_DIM 64
#define EPSV 1e-7f
#define NTILE (32 * BT)   // 3072 tile blocks

typedef _Float16 half4v __attribute__((ext_vector_type(4)));

// ---------------- dispatch 1: zero deg ----------------
__global__ __launch_bounds__(256) void k_zero(int* __restrict__ deg) {
    deg[blockIdx.x * 256 + threadIdx.x] = 0;
}

// ---- dispatch 2: transpose [B,C,T,N]->h16[bt][n][c]  +  deg count  +  ef->fp16 ----
__global__ __launch_bounds__(256) void k_trans(const float* __restrict__ nf, _Float16* __restrict__ h,
                                               const int* __restrict__ dst, int* __restrict__ deg,
                                               const float* __restrict__ ef, _Float16* __restrict__ ef16) {
    int raw = blockIdx.x;
    int tid = threadIdx.x;
    if (raw >= NTILE) {
        int aux = raw - NTILE;
        if (aux < 64) {                      // degree count (16384 edges)
            int e = aux * 256 + tid;
            atomicAdd(&deg[dst[e]], 1);
        } else {                             // ef fp32 -> fp16 (1M elements)
            int a = (aux - 64) * 256 + tid;  // 0..65535
            const float4* s4 = (const float4*)ef;
            half4v* d4 = (half4v*)ef16;
#pragma unroll
            for (int p = 0; p < 4; ++p) {
                float4 v = s4[a + p * 65536];
                half4v o;
                o.x = (_Float16)v.x; o.y = (_Float16)v.y; o.z = (_Float16)v.z; o.w = (_Float16)v.w;
                d4[a + p * 65536] = o;
            }
        }
        return;
    }
    __shared__ float lds[64][65];
    int logical = (raw & 7) * 384 + (raw >> 3);   // XCD-contiguous bt ranges
    int bt = logical >> 5;
    int nt = logical & 31;
    int b = bt / TT, t = bt - b * TT;
    int n4 = (tid & 15) << 2;
    int cr = tid >> 4;
    const float* base = nf + ((size_t)(b * CC) * TT + t) * N_NODES + nt * 64;
#pragma unroll
    for (int p = 0; p < 4; ++p) {
        int c = cr + p * 16;
        float4 v = *(const float4*)(base + (size_t)c * TT * N_NODES + n4);
        lds[c][n4 + 0] = v.x; lds[c][n4 + 1] = v.y; lds[c][n4 + 2] = v.z; lds[c][n4 + 3] = v.w;
    }
    __syncthreads();
    int c4 = (tid & 15) << 2;
    int nr = tid >> 4;
    _Float16* hb = h + ((size_t)bt * N_NODES + nt * 64) * CC;
#pragma unroll
    for (int p = 0; p < 4; ++p) {
        int n = nr + p * 16;
        half4v o;
        o.x = (_Float16)lds[c4 + 0][n]; o.y = (_Float16)lds[c4 + 1][n];
        o.z = (_Float16)lds[c4 + 2][n]; o.w = (_Float16)lds[c4 + 3][n];
        *(half4v*)(hb + (size_t)n * CC + c4) = o;
    }
}

// ---------------- dispatch 3: scan deg -> offs, cur ----------------
__global__ __launch_bounds__(1024) void k_scan(const int* __restrict__ deg, int* __restrict__ offs,
                                               int* __restrict__ cur) {
    __shared__ int sc[1024];
    int t = threadIdx.x;
    int d0 = deg[2 * t], d1 = deg[2 * t + 1];
    int p = d0 + d1;
    sc[t] = p;
    __syncthreads();
    for (int off = 1; off < 1024; off <<= 1) {
        int v = (t >= off) ? sc[t - off] : 0;
        __syncthreads();
        sc[t] += v;
        __syncthreads();
    }
    int excl = sc[t] - p;
    offs[2 * t] = excl;          cur[2 * t] = excl;
    offs[2 * t + 1] = excl + d0; cur[2 * t + 1] = excl + d0;
    if (t == 1023) offs[N_NODES] = sc[t];
}

// ---------------- dispatch 4: CSR fill ----------------
__global__ __launch_bounds__(256) void k_fill(const int* __restrict__ dst, const int* __restrict__ src,
                                              int* cur, int2* __restrict__ csr) {
    int e = blockIdx.x * 256 + threadIdx.x;
    int d = dst[e];
    int pos = atomicAdd(&cur[d], 1);
    csr[pos] = make_int2(e, src[e]);
}

// ---------------- dispatch 5: fused aggregate + matmul + transposed store ----------------
// Phase 1: wave w, lane=c; 16 nodes/wave in 4 groups of 4 independent chains.
//          Software-pipelined: iteration k's math overlaps iteration k+1's csr s_load
//          AND h/ef gathers. All indices wave-uniform (SALU/s_load); no max-tracking.
// Phase 2: lane=n; W/bias via uniform s_loads; coalesced transposed store.
__global__ __launch_bounds__(256, 6) void k_agg(const _Float16* __restrict__ h,
                                                const int* __restrict__ offs,
                                                const int2* __restrict__ csr,
                                                const _Float16* __restrict__ ef16,
                                                const float* __restrict__ W,
                                                const float* __restrict__ bias,
                                                float* __restrict__ out) {
    __shared__ float fs[64 * 64];     // XOR-swizzled tile of (h + agg)

    int tid = threadIdx.x;
    int raw = blockIdx.x;
    int logical = (raw & 7) * 384 + (raw >> 3);   // same XCD mapping as transpose
    int bt = logical >> 5;
    int nt = logical & 31;
    int b = bt / TT, t = bt - b * TT;
    int wave = tid >> 6, lane = tid & 63;
    int wbase = __builtin_amdgcn_readfirstlane(wave * 16);
    int ntb = __builtin_amdgcn_readfirstlane(nt * 64);

    const _Float16* hslice = h + (size_t)bt * (N_NODES * CC);

    for (int g = 0; g < 4; ++g) {
        int nb = ntb + wbase + g * 4;
        int kk[4], ke[4];
        bool on[4];
        float den[4], ws[4], hn[4], hs[4], ev[4];
#pragma unroll
        for (int j = 0; j < 4; ++j) {
            kk[j] = offs[nb + j];                      // uniform -> s_load
            ke[j] = offs[nb + j + 1];
            den[j] = 0.f; ws[j] = 0.f;
            hn[j] = (float)(hslice + (nb + j) * CC)[lane];
            on[j] = kk[j] < ke[j];
            if (on[j]) {                               // prologue: gather edge 0
                int2 pr = csr[kk[j]];                  // uniform -> s_load_dwordx2
                hs[j] = (float)(hslice + pr.y * CC)[lane];
                ev[j] = (float)(ef16 + pr.x * CC)[lane];
            }
        }
        while (on[0] || on[1] || on[2] || on[3]) {
            float chs[4], cev[4];
            bool con[4];
#pragma unroll
            for (int j = 0; j < 4; ++j) {              // rotate pipeline regs
                con[j] = on[j]; chs[j] = hs[j]; cev[j] = ev[j];
                kk[j] += on[j] ? 1 : 0;
                on[j] = on[j] && (kk[j] < ke[j]);
            }
#pragma unroll
            for (int j = 0; j < 4; ++j) {              // issue NEXT iteration's gathers
                if (on[j]) {
                    int2 pr = csr[kk[j]];
                    hs[j] = (float)(hslice + pr.y * CC)[lane];
                    ev[j] = (float)(ef16 + pr.x * CC)[lane];
                }
            }
#pragma unroll
            for (int j = 0; j < 4; ++j) {              // math on CURRENT values
                if (con[j]) {
                    float msg = fmaxf(chs[j] + cev[j], 0.f) + EPSV;
                    float pw = __expf(msg);            // softmax max cancels; msg <= ~6
                    den[j] += pw;
                    ws[j] = fmaf(pw, msg, ws[j]);
                }
            }
        }
#pragma unroll
        for (int j = 0; j < 4; ++j) {
            int nl = wbase + g * 4 + j;
            float agg = den[j] > 0.f ? ws[j] / den[j] : 0.f;
            fs[nl * 64 + (lane ^ (nl & 31))] = hn[j] + agg;
        }
    }
    __syncthreads();

    float acc[16];
#pragma unroll
    for (int j = 0; j < 16; ++j) acc[j] = bias[wbase + j];          // s_load
    for (int c = 0; c < 64; ++c) {
        float v = fs[lane * 64 + (c ^ (lane & 31))];                // conflict-free
#pragma unroll
        for (int j = 0; j < 16; ++j)
            acc[j] = fmaf(v, W[c * 64 + wbase + j], acc[j]);        // uniform -> s_load
    }
    size_t obase = ((size_t)(b * OUT_DIM + wbase) * TT + t) * N_NODES + ntb + lane;
#pragma unroll
    for (int j = 0; j < 16; ++j)
        out[obase + (size_t)j * (TT * N_NODES)] = acc[j];
}

extern "C" void kernel_launch(void* const* d_in, const int* in_sizes, int n_in,
                              void* d_out, int out_size, void* d_ws, size_t ws_size,
                              hipStream_t stream) {
    const float* nf  = (const float*)d_in[0];   // [B,C,T,N]
    const float* ef  = (const float*)d_in[1];   // [E,1,1,C]
    const int*   src = (const int*)d_in[2];
    const int*   dst = (const int*)d_in[3];
    const float* W   = (const float*)d_in[4];   // [C,OUT]
    const float* bia = (const float*)d_in[5];   // [OUT]
    float* out = (float*)d_out;

    _Float16* h    = (_Float16*)d_ws;                        // BT*N*C halves = 24 MiB
    _Float16* ef16 = h + (size_t)BT * N_NODES * CC;          // E*C halves = 2 MiB
    int2* csr      = (int2*)(ef16 + (size_t)N_EDGES * CC);   // 8B-aligned
    int* deg       = (int*)(csr + N_EDGES);
    int* offs      = deg + N_NODES;                          // N+1
    int* cur       = offs + (N_NODES + 1);

    k_zero<<<N_NODES / 256, 256, 0, stream>>>(deg);
    k_trans<<<NTILE + 64 + 256, 256, 0, stream>>>(nf, h, dst, deg, ef, ef16);
    k_scan<<<1, 1024, 0, stream>>>(deg, offs, cur);
    k_fill<<<N_EDGES / 256, 256, 0, stream>>>(dst, src, cur, csr);
    k_agg<<<NTILE, 256, 0, stream>>>(h, offs, csr, ef16, W, bia, out);
}

// Round 9
// 181.070 us; speedup vs baseline: 1.6765x; 1.4445x over previous
//
#include <hip/hip_runtime.h>

#define N_NODES 2048
#define N_EDGES 16384
#define TT 12
#define BT 96          // B*T
#define CC 64
#define OUT_DIM 64
#define EPSV 1e-7f
#define NTILE (32 * BT)   // 3072 tile blocks

typedef _Float16 half4v __attribute__((ext_vector_type(4)));

// ---- dispatch 2: transpose [B,C,T,N]->h16[bt][n][c]  +  deg count  +  ef->fp16 ----
__global__ __launch_bounds__(256) void k_trans(const float* __restrict__ nf, _Float16* __restrict__ h,
                                               const int* __restrict__ dst, int* __restrict__ deg,
                                               const float* __restrict__ ef, _Float16* __restrict__ ef16) {
    int raw = blockIdx.x;
    int tid = threadIdx.x;
    if (raw >= NTILE) {
        int aux = raw - NTILE;
        if (aux < 64) {                      // degree count (16384 edges)
            int e = aux * 256 + tid;
            atomicAdd(&deg[dst[e]], 1);
        } else {                             // ef fp32 -> fp16 (1M elements)
            int a = (aux - 64) * 256 + tid;  // 0..65535
            const float4* s4 = (const float4*)ef;
            half4v* d4 = (half4v*)ef16;
#pragma unroll
            for (int p = 0; p < 4; ++p) {
                float4 v = s4[a + p * 65536];
                half4v o;
                o.x = (_Float16)v.x; o.y = (_Float16)v.y; o.z = (_Float16)v.z; o.w = (_Float16)v.w;
                d4[a + p * 65536] = o;
            }
        }
        return;
    }
    __shared__ float lds[64][65];
    int logical = (raw & 7) * 384 + (raw >> 3);   // XCD-contiguous bt ranges
    int bt = logical >> 5;
    int nt = logical & 31;
    int b = bt / TT, t = bt - b * TT;
    int n4 = (tid & 15) << 2;
    int cr = tid >> 4;
    const float* base = nf + ((size_t)(b * CC) * TT + t) * N_NODES + nt * 64;
#pragma unroll
    for (int p = 0; p < 4; ++p) {
        int c = cr + p * 16;
        float4 v = *(const float4*)(base + (size_t)c * TT * N_NODES + n4);
        lds[c][n4 + 0] = v.x; lds[c][n4 + 1] = v.y; lds[c][n4 + 2] = v.z; lds[c][n4 + 3] = v.w;
    }
    __syncthreads();
    int c4 = (tid & 15) << 2;
    int nr = tid >> 4;
    _Float16* hb = h + ((size_t)bt * N_NODES + nt * 64) * CC;
#pragma unroll
    for (int p = 0; p < 4; ++p) {
        int n = nr + p * 16;
        half4v o;
        o.x = (_Float16)lds[c4 + 0][n]; o.y = (_Float16)lds[c4 + 1][n];
        o.z = (_Float16)lds[c4 + 2][n]; o.w = (_Float16)lds[c4 + 3][n];
        *(half4v*)(hb + (size_t)n * CC + c4) = o;
    }
}

// ---------------- dispatch 3: scan deg -> offs, cur (wave-shuffle scan) ----------------
__global__ __launch_bounds__(1024) void k_scan(const int* __restrict__ deg, int* __restrict__ offs,
                                               int* __restrict__ cur) {
    __shared__ int wsum[16];
    int t = threadIdx.x;
    int lane = t & 63, w = t >> 6;
    int d0 = deg[2 * t], d1 = deg[2 * t + 1];
    int p = d0 + d1;
    int x = p;
#pragma unroll
    for (int s = 1; s < 64; s <<= 1) {
        int v = __shfl_up(x, s, 64);
        if (lane >= s) x += v;
    }
    if (lane == 63) wsum[w] = x;
    __syncthreads();
    if (w == 0 && lane < 16) {
        int y = wsum[lane];
#pragma unroll
        for (int s = 1; s < 16; s <<= 1) {
            int v = __shfl_up(y, s, 64);
            if (lane >= s) y += v;
        }
        wsum[lane] = y;
    }
    __syncthreads();
    int incl = ((w > 0) ? wsum[w - 1] : 0) + x;
    int excl = incl - p;
    offs[2 * t] = excl;          cur[2 * t] = excl;
    offs[2 * t + 1] = excl + d0; cur[2 * t + 1] = excl + d0;
    if (t == 1023) offs[N_NODES] = incl;
}

// ---------------- dispatch 4: CSR fill (+ zero the padding slots) ----------------
__global__ __launch_bounds__(256) void k_fill(const int* __restrict__ dst, const int* __restrict__ src,
                                              int* cur, int2* __restrict__ csr) {
    int e = blockIdx.x * 256 + threadIdx.x;
    if (blockIdx.x == 0 && threadIdx.x < 16)
        csr[N_EDGES + threadIdx.x] = make_int2(0, 0);   // pad: harmless (src 0), math is guarded
    int d = dst[e];
    int pos = atomicAdd(&cur[d], 1);
    csr[pos] = make_int2(e, src[e]);
}

// ---------------- dispatch 5: fused aggregate + matmul + transposed store ----------------
// Phase 1: wave w, lane=c. Wave owns 16 nodes = ONE contiguous CSR range [offs[nb],offs[nb+16]).
//          Flat walk in chunks of 4 edges, A/B double-buffered gathers, zero imbalance.
//          Segment boundaries detected scalar-side (while k>=nxt -> flush into LDS tile).
// Phase 2: lane=n; W/bias via uniform s_loads; coalesced transposed store.
__global__ __launch_bounds__(256, 6) void k_agg(const _Float16* __restrict__ h,
                                                const int* __restrict__ offs,
                                                const int2* __restrict__ csr,
                                                const _Float16* __restrict__ ef16,
                                                const float* __restrict__ W,
                                                const float* __restrict__ bias,
                                                float* __restrict__ out) {
    __shared__ float fs[64 * 64];     // XOR-swizzled tile; pre-loaded with hn, flushes ADD agg

    int tid = threadIdx.x;
    int raw = blockIdx.x;
    int logical = (raw & 7) * 384 + (raw >> 3);   // XCD-contiguous bt ranges
    int bt = logical >> 5;
    int nt = logical & 31;
    int b = bt / TT, t = bt - b * TT;
    int wave = tid >> 6, lane = tid & 63;
    int wbase = __builtin_amdgcn_readfirstlane(wave * 16);
    int ntb = __builtin_amdgcn_readfirstlane(nt * 64);
    int nb = ntb + wbase;

    const _Float16* hslice = h + (size_t)bt * (N_NODES * CC);

    // pre-store hn for this wave's 16 rows
#pragma unroll
    for (int i = 0; i < 16; ++i) {
        int row = wbase + i;
        fs[row * 64 + (lane ^ (row & 31))] = (float)(hslice + (nb + i) * CC)[lane];
    }

    int kk  = __builtin_amdgcn_readfirstlane(offs[nb]);
    int end = __builtin_amdgcn_readfirstlane(offs[nb + 16]);
    int curn = 0;                                  // local node being accumulated
    int nxt = __builtin_amdgcn_readfirstlane(offs[nb + 1]);
    float den = 0.f, ws = 0.f;

    float hsA[4], evA[4], hsB[4], evB[4];

#define LOADCHUNK(HS, EV, K)                                            \
    {                                                                   \
        _Pragma("unroll")                                               \
        for (int i = 0; i < 4; ++i) {                                   \
            int2 pr = csr[(K) + i];        /* uniform -> s_load */      \
            HS[i] = (float)(hslice + pr.y * CC)[lane];                  \
            EV[i] = (float)(ef16 + pr.x * CC)[lane];                    \
        }                                                               \
    }

#define FLUSH()                                                         \
    {                                                                   \
        int row = wbase + curn;                                         \
        float agg = den > 0.f ? ws / den : 0.f;                         \
        fs[row * 64 + (lane ^ (row & 31))] += agg;                      \
        den = 0.f; ws = 0.f;                                            \
        curn++;                                                         \
        nxt = offs[nb + curn + 1];                                      \
    }

#define PROCESS(HS, EV, K)                                              \
    {                                                                   \
        _Pragma("unroll")                                               \
        for (int i = 0; i < 4; ++i) {                                   \
            if ((K) + i < end) {                                        \
                while ((K) + i >= nxt) FLUSH();                         \
                float msg = fmaxf(HS[i] + EV[i], 0.f) + EPSV;           \
                float pw = __expf(msg);   /* softmax max cancels */     \
                den += pw;                                              \
                ws = fmaf(pw, msg, ws);                                 \
            }                                                           \
        }                                                               \
    }

    if (kk < end) {
        LOADCHUNK(hsA, evA, kk);
        while (true) {
            LOADCHUNK(hsB, evB, kk + 4);          // pad-safe (csr has 16 zero slots)
            PROCESS(hsA, evA, kk);
            kk += 4;
            if (kk >= end) break;
            LOADCHUNK(hsA, evA, kk + 4);
            PROCESS(hsB, evB, kk);
            kk += 4;
            if (kk >= end) break;
        }
    }
    while (curn < 16) {                           // flush trailing (and empty) nodes
        int row = wbase + curn;
        float agg = den > 0.f ? ws / den : 0.f;
        fs[row * 64 + (lane ^ (row & 31))] += agg;
        den = 0.f; ws = 0.f;
        curn++;
    }
    __syncthreads();

    float acc[16];
#pragma unroll
    for (int j = 0; j < 16; ++j) acc[j] = bias[wbase + j];          // s_load
    for (int c = 0; c < 64; ++c) {
        float v = fs[lane * 64 + (c ^ (lane & 31))];                // conflict-free
#pragma unroll
        for (int j = 0; j < 16; ++j)
            acc[j] = fmaf(v, W[c * 64 + wbase + j], acc[j]);        // uniform -> s_load
    }
    size_t obase = ((size_t)(b * OUT_DIM + wbase) * TT + t) * N_NODES + ntb + lane;
#pragma unroll
    for (int j = 0; j < 16; ++j)
        out[obase + (size_t)j * (TT * N_NODES)] = acc[j];
}

extern "C" void kernel_launch(void* const* d_in, const int* in_sizes, int n_in,
                              void* d_out, int out_size, void* d_ws, size_t ws_size,
                              hipStream_t stream) {
    const float* nf  = (const float*)d_in[0];   // [B,C,T,N]
    const float* ef  = (const float*)d_in[1];   // [E,1,1,C]
    const int*   src = (const int*)d_in[2];
    const int*   dst = (const int*)d_in[3];
    const float* W   = (const float*)d_in[4];   // [C,OUT]
    const float* bia = (const float*)d_in[5];   // [OUT]
    float* out = (float*)d_out;

    _Float16* h    = (_Float16*)d_ws;                        // BT*N*C halves = 24 MiB
    _Float16* ef16 = h + (size_t)BT * N_NODES * CC;          // E*C halves = 2 MiB
    int2* csr      = (int2*)(ef16 + (size_t)N_EDGES * CC);   // E+16 pairs (16 = pad)
    int* deg       = (int*)(csr + N_EDGES + 16);
    int* offs      = deg + N_NODES;                          // N+1
    int* cur       = offs + (N_NODES + 1);

    hipMemsetAsync(deg, 0, sizeof(int) * N_NODES, stream);
    k_trans<<<NTILE + 64 + 256, 256, 0, stream>>>(nf, h, dst, deg, ef, ef16);
    k_scan<<<1, 1024, 0, stream>>>(deg, offs, cur);
    k_fill<<<N_EDGES / 256, 256, 0, stream>>>(dst, src, cur, csr);
    k_agg<<<NTILE, 256, 0, stream>>>(h, offs, csr, ef16, W, bia, out);
}